// Round 7
// baseline (96.738 us; speedup 1.0000x reference)
//
#include <hip/hip_runtime.h>
#include <hip/hip_fp16.h>
#include <math.h>

typedef _Float16 f16x8 __attribute__((ext_vector_type(8)));
typedef float f32x4 __attribute__((ext_vector_type(4)));

#define NS 4
#define HID 512
#define IN_DIM 342
#define OUT_DIM 311
#define BATCH 1024
#define INP 352            // IN_DIM padded (virtual)
#define K0V 1408
#define K12V 2048
#define XROW 343

// workspace float offsets (~11.8 MB)
#define OFF_H1X 0                       // 1024*2048 f16
#define OFF_H2X (OFF_H1X + 1048576)     // 1024*2048 f16
#define OFF_W1H (OFF_H2X + 1048576)     // 512*2048 f16
#define OFF_W2H (OFF_W1H + 524288)      // 320*2048 f16

__device__ __forceinline__ void coefs4(float phase, float* c) {
    float ps = (float)NS * phase;
    float mu = ps - floorf(ps);
    int i1 = ((int)ps) & 3;
    float mu2 = mu*mu, mu3 = mu2*mu;
    float r0 =  1.5f*mu3 - 2.5f*mu2 + 1.0f;
    float r1 = -1.5f*mu3 + 2.0f*mu2 + 0.5f*mu;
    float r2 =  0.5f*mu3 - 0.5f*mu2;
    float r3 = -0.5f*mu3 +      mu2 - 0.5f*mu;
    #pragma unroll
    for (int s = 0; s < 4; ++s) {
        int rel = (s - i1) & 3;
        c[s] = (rel==0)?r0:(rel==1)?r1:(rel==2)?r2:r3;
    }
}

// BM=32 x BN=32, BK=128, 256 threads (4 waves): split-K g=wid>>1, wn=wid&1.
// LDS: sA 8KB | sB 8KB per buffer, double buffered (32KB) -> 2 blocks/CU.
// LAYER 0: A = f16(c_s*x), B = f16(W0 f32) staged on the fly; blocks>=512 repack W1h/W2h.
// LAYER 1/2: A = prescaled f16, B = f16 repacked weights.
template<int LAYER>
__global__ __launch_bounds__(256) void pfn_gemm(
    const float* __restrict__ x,
    const float* __restrict__ Wf,      // L0: W0 (f32)
    const __half* __restrict__ Ah,     // L1/2: prescaled activations
    const __half* __restrict__ Wh,     // L1/2: f16 weights
    const float* __restrict__ bias,
    __half* __restrict__ outH,
    float* __restrict__ outF,
    const float* __restrict__ W1f, const float* __restrict__ W2f,
    __half* __restrict__ W1h, __half* __restrict__ W2h)
{
    constexpr int K  = (LAYER==0) ? K0V : K12V;
    constexpr int NB = (LAYER==2) ? OUT_DIM : HID;
    constexpr int NITER = K / 128;

    const int t = threadIdx.x;

    if (LAYER == 0 && blockIdx.x >= 512) {   // ---- weight repack blocks ----
        int j = blockIdx.x - 512;
        int half = t >> 7;                    // 2 rows per block
        int tt = t & 127;                     // 16 f16 per thread
        int k = tt * 16;
        int s = k >> 9, i = k & 511;
        f16x8 h0 = {}, h1 = {};
        __half* dst;
        if (j < 256) {                        // W1
            int o = j*2 + half;
            const float* src = W1f + ((size_t)s*HID + o)*HID + i;
            #pragma unroll
            for (int q=0;q<8;++q) h0[q] = (_Float16)src[q];
            #pragma unroll
            for (int q=0;q<8;++q) h1[q] = (_Float16)src[8+q];
            dst = W1h + (size_t)o*K12V + k;
        } else {                              // W2 (rows >=311 zero)
            int o = (j-256)*2 + half;
            if (o < OUT_DIM) {
                const float* src = W2f + ((size_t)s*OUT_DIM + o)*HID + i;
                #pragma unroll
                for (int q=0;q<8;++q) h0[q] = (_Float16)src[q];
                #pragma unroll
                for (int q=0;q<8;++q) h1[q] = (_Float16)src[8+q];
            }
            dst = W2h + (size_t)o*K12V + k;
        }
        *(f16x8*)(dst)     = h0;
        *(f16x8*)(dst + 8) = h1;
        return;
    }

    // ---------------- GEMM ----------------
    __shared__ __align__(16) char lbuf[2][16384];

    const int tile = blockIdx.x;
    const int m0 = (tile & 31) * 32;
    const int n0 = (tile >> 5) * 32;
    const int lane = t & 63;
    const int wid  = t >> 6;
    const int g    = wid >> 1;     // split-K group
    const int wn   = wid & 1;      // 16-col half

    // staging: thread -> row t>>3 (0..31) of BOTH tiles, 16-f16 chunk t&7
    const int sRow = t >> 3;
    const int sC   = t & 7;
    const int swzS = (sRow & 7) << 4;
    const int aOff0 = sRow*256 + ((sC*32)      ^ swzS);
    const int aOff1 = sRow*256 + ((sC*32 + 16) ^ swzS);

    float myc[4];
    if (LAYER == 0) coefs4(x[(size_t)(m0+sRow)*XROW + IN_DIM], myc);

    float ar[16], br[16];     // L0 reg staging (f32, scaled/converted at store)
    uint4 arh[2], brh[2];     // L1/2 reg staging

    auto loadA = [&](int k0) {
        if (LAYER == 0) {
            int k = k0 + sC*16;
            int s = k / INP;
            int i = k - s*INP;
            const float* src = x + (size_t)(m0+sRow)*XROW + i;
            float sc = myc[s];
            if (i + 16 <= IN_DIM) {
                #pragma unroll
                for (int q=0;q<16;++q) ar[q] = src[q]*sc;
            } else {
                #pragma unroll
                for (int q=0;q<16;++q) { float v=0.f; if (i+q < IN_DIM) v = src[q]*sc; ar[q]=v; }
            }
        } else {
            const __half* src = Ah + (size_t)(m0+sRow)*K12V + k0 + sC*16;
            arh[0] = *(const uint4*)(src);
            arh[1] = *(const uint4*)(src + 8);
        }
    };
    auto loadB = [&](int k0) {
        if (LAYER == 0) {
            int k = k0 + sC*16;
            int s = k / INP;
            int i = k - s*INP;
            const float* src = Wf + ((size_t)s*HID + (n0+sRow))*IN_DIM + i;
            if (i + 16 <= IN_DIM) {
                #pragma unroll
                for (int q=0;q<16;++q) br[q] = src[q];
            } else {
                #pragma unroll
                for (int q=0;q<16;++q) { float v=0.f; if (i+q < IN_DIM) v = src[q]; br[q]=v; }
            }
        } else {
            const __half* src = Wh + (size_t)(n0+sRow)*K12V + k0 + sC*16;
            brh[0] = *(const uint4*)(src);
            brh[1] = *(const uint4*)(src + 8);
        }
    };
    auto storeA = [&](char* buf) {
        if (LAYER == 0) {
            f16x8 h0, h1;
            #pragma unroll
            for (int q=0;q<8;++q) { h0[q]=(_Float16)ar[q]; h1[q]=(_Float16)ar[8+q]; }
            *(f16x8*)(buf + aOff0) = h0;
            *(f16x8*)(buf + aOff1) = h1;
        } else {
            *(uint4*)(buf + aOff0) = arh[0];
            *(uint4*)(buf + aOff1) = arh[1];
        }
    };
    auto storeB = [&](char* buf) {
        if (LAYER == 0) {
            f16x8 h0, h1;
            #pragma unroll
            for (int q=0;q<8;++q) { h0[q]=(_Float16)br[q]; h1[q]=(_Float16)br[8+q]; }
            *(f16x8*)(buf + 8192 + aOff0) = h0;
            *(f16x8*)(buf + 8192 + aOff1) = h1;
        } else {
            *(uint4*)(buf + 8192 + aOff0) = brh[0];
            *(uint4*)(buf + 8192 + aOff1) = brh[1];
        }
    };

    f32x4 acc[2] = {};

    loadA(0); loadB(0);
    storeA(lbuf[0]); storeB(lbuf[0]);

    for (int it = 0; it < NITER; ++it) {
        __syncthreads();
        if (it + 1 < NITER) { loadA((it+1)*128); loadB((it+1)*128); }
        {   // compute on current buffer
            const char* sA = lbuf[it & 1];
            const char* sB = lbuf[it & 1] + 8192;
            #pragma unroll
            for (int kk = 0; kk < 2; ++kk) {
                const int kb = g*128 + kk*64 + (lane>>4)*16;
                const int oo = wn*16 + (lane&15);
                f16x8 bf = *(const f16x8*)(sB + oo*256 + (kb ^ ((oo&7)<<4)));
                #pragma unroll
                for (int mi = 0; mi < 2; ++mi) {
                    const int rr = mi*16 + (lane&15);
                    f16x8 af = *(const f16x8*)(sA + rr*256 + (kb ^ ((rr&7)<<4)));
                    acc[mi] = __builtin_amdgcn_mfma_f32_16x16x32_f16(af, bf, acc[mi], 0, 0, 0);
                }
            }
        }
        if (it + 1 < NITER) { storeA(lbuf[(it+1)&1]); storeB(lbuf[(it+1)&1]); }
    }

    // ---- split-K reduction (g1 -> LDS, g0 adds) ----
    __syncthreads();
    float* red = (float*)lbuf[0];            // 32x32 f32 = 4KB
    if (g == 1) {
        #pragma unroll
        for (int mi = 0; mi < 2; ++mi)
            #pragma unroll
            for (int r = 0; r < 4; ++r)
                red[(mi*16 + (lane>>4)*4 + r)*32 + wn*16 + (lane&15)] = acc[mi][r];
    }
    __syncthreads();
    if (g != 0) return;
    #pragma unroll
    for (int mi = 0; mi < 2; ++mi)
        #pragma unroll
        for (int r = 0; r < 4; ++r)
            acc[mi][r] += red[(mi*16 + (lane>>4)*4 + r)*32 + wn*16 + (lane&15)];

    // ---- epilogue ----
    #pragma unroll
    for (int mi = 0; mi < 2; ++mi) {
        #pragma unroll
        for (int r = 0; r < 4; ++r) {
            const int row = m0 + mi*16 + (lane>>4)*4 + r;
            float c[4];
            coefs4(x[(size_t)row*XROW + IN_DIM], c);
            const int col = n0 + wn*16 + (lane&15);
            float v = acc[mi][r];
            if (LAYER == 2) {
                if (col < OUT_DIM) {
                    float bi = c[0]*bias[col] + c[1]*bias[NB+col]
                             + c[2]*bias[2*NB+col] + c[3]*bias[3*NB+col];
                    outF[(size_t)row*OUT_DIM + col] = v + bi;
                }
            } else {
                float bi = c[0]*bias[col] + c[1]*bias[NB+col]
                         + c[2]*bias[2*NB+col] + c[3]*bias[3*NB+col];
                v += bi;
                v = (v > 0.f) ? v : expm1f(v);
                size_t o = (size_t)row*K12V + col;
                outH[o        ] = __float2half(c[0]*v);
                outH[o +   HID] = __float2half(c[1]*v);
                outH[o + 2*HID] = __float2half(c[2]*v);
                outH[o + 3*HID] = __float2half(c[3]*v);
            }
        }
    }
}

extern "C" void kernel_launch(void* const* d_in, const int* in_sizes, int n_in,
                              void* d_out, int out_size, void* d_ws, size_t ws_size,
                              hipStream_t stream) {
    const float* x  = (const float*)d_in[0];
    const float* W0 = (const float*)d_in[1];
    const float* W1 = (const float*)d_in[2];
    const float* W2 = (const float*)d_in[3];
    const float* b0 = (const float*)d_in[4];
    const float* b1 = (const float*)d_in[5];
    const float* b2 = (const float*)d_in[6];
    float* out = (float*)d_out;
    float* ws  = (float*)d_ws;

    __half* H1x = (__half*)(ws + OFF_H1X);
    __half* H2x = (__half*)(ws + OFF_H2X);
    __half* W1h = (__half*)(ws + OFF_W1H);
    __half* W2h = (__half*)(ws + OFF_W2H);

    // L0 GEMM (512 tiles) + W1/W2 repack (416 blocks) in one launch
    pfn_gemm<0><<<dim3(928), dim3(256), 0, stream>>>(
        x, W0, nullptr, nullptr, b0, H1x, nullptr, W1, W2, W1h, W2h);
    pfn_gemm<1><<<dim3(512), dim3(256), 0, stream>>>(
        x, nullptr, H1x, W1h, b1, H2x, nullptr, nullptr, nullptr, nullptr, nullptr);
    pfn_gemm<2><<<dim3(320), dim3(256), 0, stream>>>(
        x, nullptr, H2x, W2h, b2, nullptr, out, nullptr, nullptr, nullptr, nullptr);
}

// Round 8
// 71.911 us; speedup vs baseline: 1.3452x; 1.3452x over previous
//
#include <hip/hip_runtime.h>
#include <hip/hip_fp16.h>
#include <math.h>

typedef _Float16 f16x8 __attribute__((ext_vector_type(8)));
typedef float f32x4 __attribute__((ext_vector_type(4)));

#define NS 4
#define HID 512
#define IN_DIM 342
#define OUT_DIM 311
#define BATCH 1024
#define INP 352            // IN_DIM padded (virtual)
#define K0V 1408
#define K12V 2048
#define XROW 343

// workspace float offsets (~11.8 MB)
#define OFF_H1X 0                       // 1024*2048 f16
#define OFF_H2X (OFF_H1X + 1048576)     // 1024*2048 f16
#define OFF_W1H (OFF_H2X + 1048576)     // 512*2048 f16
#define OFF_W2H (OFF_W1H + 524288)      // 320*2048 f16

__device__ __forceinline__ void coefs4(float phase, float* c) {
    float ps = (float)NS * phase;
    float mu = ps - floorf(ps);
    int i1 = ((int)ps) & 3;
    float mu2 = mu*mu, mu3 = mu2*mu;
    float r0 =  1.5f*mu3 - 2.5f*mu2 + 1.0f;        // rel 0 (s==i1)
    float r1 = -1.5f*mu3 + 2.0f*mu2 + 0.5f*mu;     // rel 1
    float r2 =  0.5f*mu3 - 0.5f*mu2;               // rel 2
    float r3 = -0.5f*mu3 +      mu2 - 0.5f*mu;     // rel 3
    #pragma unroll
    for (int s = 0; s < 4; ++s) {
        int rel = (s - i1) & 3;
        c[s] = (rel==0)?r0:(rel==1)?r1:(rel==2)?r2:r3;
    }
}

// ---- R4-geometry GEMM: BM=32 x BN=64, BK=64, 256 threads (4 waves),
// wm=wid>>1 (16-row half), wn=wid&1 (32-col half), acc[2], LDS double-buffer
// (2x12KB), 1 barrier/iter, XOR swizzle both sides.
// LAYER 0: A staged from f32 x (cubic prescale), B from f32 W0 (L2-resident);
//          blocks >= 256 repack W1h/W2h instead.
// LAYER 1/2: A prescaled f16, B repacked f16.
template<int LAYER>
__global__ __launch_bounds__(256) void pfn_gemm(
    const float* __restrict__ x,
    const float* __restrict__ W0f,
    const __half* __restrict__ Ah,
    const __half* __restrict__ Wh,
    const float* __restrict__ bias,
    __half* __restrict__ outH,
    float* __restrict__ outF,
    const float* __restrict__ W1f, const float* __restrict__ W2f,
    __half* __restrict__ W1h, __half* __restrict__ W2h)
{
    constexpr int K  = (LAYER==0) ? K0V : K12V;
    constexpr int NB = (LAYER==2) ? OUT_DIM : HID;
    constexpr int NITER = K / 64;

    const int t = threadIdx.x;

    if (LAYER == 0 && blockIdx.x >= 256) {   // ---- W1/W2 repack blocks ----
        int j = blockIdx.x - 256;             // 0..415
        int half = t >> 7;                    // 2 rows per block
        int tt = t & 127;                     // 16 f16 per thread (covers 2048)
        int k = tt * 16;
        int s = k >> 9, i = k & 511;
        f16x8 h0 = {}, h1 = {};
        __half* dst;
        if (j < 256) {                        // W1: o = 0..511
            int o = j*2 + half;
            const float* src = W1f + ((size_t)s*HID + o)*HID + i;
            float4 v0 = *(const float4*)(src);
            float4 v1 = *(const float4*)(src + 4);
            float4 v2 = *(const float4*)(src + 8);
            float4 v3 = *(const float4*)(src + 12);
            h0[0]=(_Float16)v0.x; h0[1]=(_Float16)v0.y; h0[2]=(_Float16)v0.z; h0[3]=(_Float16)v0.w;
            h0[4]=(_Float16)v1.x; h0[5]=(_Float16)v1.y; h0[6]=(_Float16)v1.z; h0[7]=(_Float16)v1.w;
            h1[0]=(_Float16)v2.x; h1[1]=(_Float16)v2.y; h1[2]=(_Float16)v2.z; h1[3]=(_Float16)v2.w;
            h1[4]=(_Float16)v3.x; h1[5]=(_Float16)v3.y; h1[6]=(_Float16)v3.z; h1[7]=(_Float16)v3.w;
            dst = W1h + (size_t)o*K12V + k;
        } else {                              // W2: o = 0..319 (>=311 stays 0)
            int o = (j-256)*2 + half;
            if (o < OUT_DIM) {
                const float* src = W2f + ((size_t)s*OUT_DIM + o)*HID + i;
                float4 v0 = *(const float4*)(src);
                float4 v1 = *(const float4*)(src + 4);
                float4 v2 = *(const float4*)(src + 8);
                float4 v3 = *(const float4*)(src + 12);
                h0[0]=(_Float16)v0.x; h0[1]=(_Float16)v0.y; h0[2]=(_Float16)v0.z; h0[3]=(_Float16)v0.w;
                h0[4]=(_Float16)v1.x; h0[5]=(_Float16)v1.y; h0[6]=(_Float16)v1.z; h0[7]=(_Float16)v1.w;
                h1[0]=(_Float16)v2.x; h1[1]=(_Float16)v2.y; h1[2]=(_Float16)v2.z; h1[3]=(_Float16)v2.w;
                h1[4]=(_Float16)v3.x; h1[5]=(_Float16)v3.y; h1[6]=(_Float16)v3.z; h1[7]=(_Float16)v3.w;
            }
            dst = W2h + (size_t)o*K12V + k;
        }
        *(f16x8*)(dst)     = h0;
        *(f16x8*)(dst + 8) = h1;
        return;
    }

    // ---------------- GEMM ----------------
    __shared__ __align__(16) char lbuf[2][12288];    // sA 4KB | sB 8KB

    const int bid = blockIdx.x;
    const int n0 = (LAYER==2) ? (bid % 5)*64 : (bid & 7)*64;
    const int m0 = (LAYER==2) ? (bid / 5)*32 : (bid >> 3)*32;

    const int lane = t & 63;
    const int wid  = t >> 6;
    const int wm   = wid >> 1;
    const int wn   = wid & 1;

    // A staging: thread -> row t>>3 (0..31), 8-f16 chunk t&7
    const int aRow = t >> 3;
    const int aC   = t & 7;
    const int aOff = aRow*128 + ((aC*16) ^ ((aRow&7)<<4));
    // B staging: thread -> row t>>2 (0..63), 16-f16 chunk t&3
    const int bRow = t >> 2;
    const int bC   = t & 3;
    const int bOff0 = 4096 + bRow*128 + ((bC*32)        ^ ((bRow&7)<<4));
    const int bOff1 = 4096 + bRow*128 + (((bC*32) + 16) ^ ((bRow&7)<<4));

    float myc[4];
    if (LAYER == 0) coefs4(x[(size_t)(m0+aRow)*XROW + IN_DIM], myc);

    float ar[8], br[16];       // L0 f32 staging regs
    uint4 va, vb0, vb1;        // L1/2 f16 staging regs

    auto loadAB = [&](int k0) {
        if (LAYER == 0) {
            {   // A from x
                int k = k0 + aC*8;
                int s = k / INP;
                int i = k - s*INP;
                const float* src = x + (size_t)(m0+aRow)*XROW + i;
                float sc = myc[s];
                if (i + 8 <= IN_DIM) {
                    #pragma unroll
                    for (int q=0;q<8;++q) ar[q] = src[q]*sc;
                } else {
                    #pragma unroll
                    for (int q=0;q<8;++q) { float v=0.f; if (i+q < IN_DIM) v = src[q]*sc; ar[q]=v; }
                }
            }
            {   // B from W0 (f32, L2-resident)
                int k = k0 + bC*16;
                int s = k / INP;
                int i = k - s*INP;
                const float* src = W0f + ((size_t)s*HID + (n0+bRow))*IN_DIM + i;
                if (i + 16 <= IN_DIM) {
                    #pragma unroll
                    for (int q=0;q<16;++q) br[q] = src[q];
                } else {
                    #pragma unroll
                    for (int q=0;q<16;++q) { float v=0.f; if (i+q < IN_DIM) v = src[q]; br[q]=v; }
                }
            }
        } else {
            va  = *(const uint4*)(Ah + (size_t)(m0+aRow)*K12V + k0 + aC*8);
            const __half* src = Wh + (size_t)(n0+bRow)*K12V + k0 + bC*16;
            vb0 = *(const uint4*)(src);
            vb1 = *(const uint4*)(src + 8);
        }
    };
    auto storeAB = [&](char* buf) {
        if (LAYER == 0) {
            f16x8 ha, hb0, hb1;
            #pragma unroll
            for (int q=0;q<8;++q) { ha[q]=(_Float16)ar[q]; hb0[q]=(_Float16)br[q]; hb1[q]=(_Float16)br[8+q]; }
            *(f16x8*)(buf + aOff)  = ha;
            *(f16x8*)(buf + bOff0) = hb0;
            *(f16x8*)(buf + bOff1) = hb1;
        } else {
            *(uint4*)(buf + aOff)  = va;
            *(uint4*)(buf + bOff0) = vb0;
            *(uint4*)(buf + bOff1) = vb1;
        }
    };

    f32x4 acc[2] = {};

    loadAB(0);
    storeAB(lbuf[0]);

    for (int it = 0; it < NITER; ++it) {
        __syncthreads();
        if (it + 1 < NITER) loadAB((it+1)*64);
        const char* sA = lbuf[it & 1];
        const char* sB = lbuf[it & 1] + 4096;
        #pragma unroll
        for (int kk = 0; kk < 2; ++kk) {
            const int kb = kk*64 + (lane>>4)*16;
            const int rr = wm*16 + (lane&15);
            f16x8 af = *(const f16x8*)(sA + rr*128 + (kb ^ ((rr&7)<<4)));
            #pragma unroll
            for (int ni = 0; ni < 2; ++ni) {
                const int oo = wn*32 + ni*16 + (lane&15);
                f16x8 bf = *(const f16x8*)(sB + oo*128 + (kb ^ ((oo&7)<<4)));
                acc[ni] = __builtin_amdgcn_mfma_f32_16x16x32_f16(af, bf, acc[ni], 0, 0, 0);
            }
        }
        if (it + 1 < NITER) storeAB(lbuf[(it+1)&1]);
    }

    // ---- epilogue: recompute coefs per row, bias interp (+ELU), store ----
    #pragma unroll
    for (int r = 0; r < 4; ++r) {
        const int row = m0 + wm*16 + (lane>>4)*4 + r;
        float c[4];
        coefs4(x[(size_t)row*XROW + IN_DIM], c);
        #pragma unroll
        for (int ni = 0; ni < 2; ++ni) {
            const int col = n0 + wn*32 + ni*16 + (lane&15);
            float v = acc[ni][r];
            if (LAYER == 2) {
                if (col < OUT_DIM) {
                    float bi = c[0]*bias[col] + c[1]*bias[NB+col]
                             + c[2]*bias[2*NB+col] + c[3]*bias[3*NB+col];
                    outF[(size_t)row*OUT_DIM + col] = v + bi;
                }
            } else {
                float bi = c[0]*bias[col] + c[1]*bias[NB+col]
                         + c[2]*bias[2*NB+col] + c[3]*bias[3*NB+col];
                v += bi;
                v = (v > 0.f) ? v : expm1f(v);
                size_t o = (size_t)row*K12V + col;
                outH[o        ] = __float2half(c[0]*v);
                outH[o +   HID] = __float2half(c[1]*v);
                outH[o + 2*HID] = __float2half(c[2]*v);
                outH[o + 3*HID] = __float2half(c[3]*v);
            }
        }
    }
}

extern "C" void kernel_launch(void* const* d_in, const int* in_sizes, int n_in,
                              void* d_out, int out_size, void* d_ws, size_t ws_size,
                              hipStream_t stream) {
    const float* x  = (const float*)d_in[0];
    const float* W0 = (const float*)d_in[1];
    const float* W1 = (const float*)d_in[2];
    const float* W2 = (const float*)d_in[3];
    const float* b0 = (const float*)d_in[4];
    const float* b1 = (const float*)d_in[5];
    const float* b2 = (const float*)d_in[6];
    float* out = (float*)d_out;
    float* ws  = (float*)d_ws;

    __half* H1x = (__half*)(ws + OFF_H1X);
    __half* H2x = (__half*)(ws + OFF_H2X);
    __half* W1h = (__half*)(ws + OFF_W1H);
    __half* W2h = (__half*)(ws + OFF_W2H);

    // L0 GEMM (256 tiles) + W1/W2 repack (416 blocks) in one launch
    pfn_gemm<0><<<dim3(672), dim3(256), 0, stream>>>(
        x, W0, nullptr, nullptr, b0, H1x, nullptr, W1, W2, W1h, W2h);
    pfn_gemm<1><<<dim3(256), dim3(256), 0, stream>>>(
        x, nullptr, H1x, W1h, b1, H2x, nullptr, nullptr, nullptr, nullptr, nullptr);
    pfn_gemm<2><<<dim3(160), dim3(256), 0, stream>>>(
        x, nullptr, H2x, W2h, b2, nullptr, out, nullptr, nullptr, nullptr, nullptr);
}

// Round 9
// 45.468 us; speedup vs baseline: 2.1276x; 1.5816x over previous
//
#include <hip/hip_runtime.h>
#include <hip/hip_fp16.h>
#include <math.h>

typedef _Float16 f16x8 __attribute__((ext_vector_type(8)));
typedef float f32x4 __attribute__((ext_vector_type(4)));

#define NS 4
#define HID 512
#define IN_DIM 342
#define OUT_DIM 311
#define BATCH 1024
#define INP 352            // IN_DIM padded to mult of 32
#define K0V (NS*INP)       // 1408
#define K12V (NS*HID)      // 2048
#define XROW (IN_DIM+1)    // 343

// workspace float offsets (~11.9 MB)
#define OFF_ACOEF 0
#define OFF_X0H   4096
#define OFF_W0H   (OFF_X0H + 720896)
#define OFF_W1H   (OFF_W0H + 360448)
#define OFF_W2H   (OFF_W1H + 524288)
#define OFF_H1X   (OFF_W2H + 327680)
#define OFF_H2X   OFF_X0H      // overlays X0h+part of W0h (dead after L0)

typedef __attribute__((address_space(3))) void lds_t;
typedef __attribute__((address_space(1))) const void gvm_t;
__device__ __forceinline__ void gload16(const void* g, void* l) {
    __builtin_amdgcn_global_load_lds((gvm_t*)g, (lds_t*)l, 16, 0, 0);
}

// ---- fused prep kernel (R4-proven) ----
__global__ __launch_bounds__(256) void prep_all(
    const float* __restrict__ x,
    const float* __restrict__ W0, const float* __restrict__ W1,
    const float* __restrict__ W2,
    float* __restrict__ acoef,
    __half* __restrict__ X0h, __half* __restrict__ W0h,
    __half* __restrict__ W1h, __half* __restrict__ W2h)
{
    const int bid = blockIdx.x;
    const int t = threadIdx.x;
    if (bid < 512) {                       // W0h
        int o = bid;
        for (int k = t; k < K0V; k += 256) {
            int s = k / INP;
            int i = k - s*INP;
            float v = 0.f;
            if (i < IN_DIM) v = W0[((size_t)s*HID + o)*IN_DIM + i];
            W0h[(size_t)o*K0V + k] = __float2half(v);
        }
    } else if (bid < 1024) {               // W1h
        int o = bid - 512;
        int k = t * 8;
        int s = k >> 9, i = k & 511;
        const float* src = W1 + ((size_t)s*HID + o)*HID + i;
        float4 v0 = *(const float4*)(src);
        float4 v1 = *(const float4*)(src + 4);
        f16x8 h;
        h[0]=(_Float16)v0.x; h[1]=(_Float16)v0.y; h[2]=(_Float16)v0.z; h[3]=(_Float16)v0.w;
        h[4]=(_Float16)v1.x; h[5]=(_Float16)v1.y; h[6]=(_Float16)v1.z; h[7]=(_Float16)v1.w;
        *(f16x8*)(W1h + (size_t)o*K12V + k) = h;
    } else if (bid < 1344) {               // W2h
        int o = bid - 1024;                 // 0..319
        int k = t * 8;
        int s = k >> 9, i = k & 511;
        f16x8 h = {};
        if (o < OUT_DIM) {
            const float* src = W2 + ((size_t)s*OUT_DIM + o)*HID + i;
            float4 v0 = *(const float4*)(src);
            float4 v1 = *(const float4*)(src + 4);
            h[0]=(_Float16)v0.x; h[1]=(_Float16)v0.y; h[2]=(_Float16)v0.z; h[3]=(_Float16)v0.w;
            h[4]=(_Float16)v1.x; h[5]=(_Float16)v1.y; h[6]=(_Float16)v1.z; h[7]=(_Float16)v1.w;
        }
        *(f16x8*)(W2h + (size_t)o*K12V + k) = h;
    } else {                               // X0h + acoef
        int b = bid - 1344;
        float phase = x[(size_t)b*XROW + IN_DIM];
        float ps = (float)NS * phase;
        float mu = ps - floorf(ps);
        int i1 = ((int)ps) & (NS-1);
        float mu2 = mu*mu, mu3 = mu2*mu;
        float c1 =  1.5f*mu3 - 2.5f*mu2 + 1.0f;        // rel 0
        float c2 = -1.5f*mu3 + 2.0f*mu2 + 0.5f*mu;     // rel 1
        float c3 =  0.5f*mu3 - 0.5f*mu2;               // rel 2
        float c0 = -0.5f*mu3 +      mu2 - 0.5f*mu;     // rel 3
        if (t < 4) {
            int rel = (t - i1) & 3;
            acoef[b*4 + t] = (rel==0)?c1:(rel==1)?c2:(rel==2)?c3:c0;
        }
        for (int k = t; k < K0V; k += 256) {
            int s = k / INP;
            int i = k - s*INP;
            int rel = (s - i1) & 3;
            float sel = (rel==0)?c1:(rel==1)?c2:(rel==2)?c3:c0;
            float v = (i < IN_DIM) ? x[(size_t)b*XROW + i] * sel : 0.f;
            X0h[(size_t)b*K0V + k] = __float2half(v);
        }
    }
}

// ---- MFMA GEMM, R4 geometry (BM=32 x BN=64, BK=64, 4 waves, acc[2]) ----
// Staging via global_load_lds width-16 into a 3-buffer LDS ring, counted
// vmcnt(3) (depth-2 pipeline). LDS dest linear; global SOURCE pre-swizzled
// (XOR involution); ds_reads swizzled as before (rule #21 both-sides).
template<int LAYER>
__global__ __launch_bounds__(256) void gemm_mfma(
    const __half* __restrict__ A,
    const __half* __restrict__ Bw,
    const float* __restrict__ acoef,
    const float* __restrict__ bias,
    __half* __restrict__ outH,
    float* __restrict__ outF)
{
    constexpr int K  = (LAYER==0) ? K0V : K12V;
    constexpr int NB = (LAYER==2) ? OUT_DIM : HID;
    constexpr int NITER = K / 64;

    __shared__ __align__(16) char lbuf[3][12288];   // A 4KB | B 8KB per buf

    const int t    = threadIdx.x;
    const int lane = t & 63;
    const int wid  = t >> 6;
    const int wm   = wid >> 1;
    const int wn   = wid & 1;
    const int m0   = blockIdx.y * 32;
    const int n0   = blockIdx.x * 64;

    // A: LDS byte t*16 -> row r=t>>3, lds-chunk c=t&7; global chunk = c^(r&7)
    const int rA = t >> 3, cA = t & 7;
    const __half* aSrc = A + (size_t)(m0 + rA)*K + ((cA ^ (rA & 7)) * 8);
    // B: two 4KB halves (rows 0..31, 32..63)
    const __half* bSrc0 = Bw + (size_t)(n0 + rA)*K      + ((cA ^ (rA & 7)) * 8);
    const __half* bSrc1 = Bw + (size_t)(n0 + 32 + rA)*K + ((cA ^ (rA & 7)) * 8);
    const int wb = wid * 1024;     // wave-uniform LDS sub-base

    f32x4 acc[2] = {};

    auto stage = [&](int it) {
        char* base = lbuf[it % 3];
        const int ko = it * 64;
        gload16(aSrc  + ko, base        + wb);
        gload16(bSrc0 + ko, base + 4096 + wb);
        gload16(bSrc1 + ko, base + 8192 + wb);
    };

    stage(0);
    stage(1);

    for (int it = 0; it < NITER; ++it) {
        if (it + 1 < NITER) asm volatile("s_waitcnt vmcnt(3)" ::: "memory");
        else                asm volatile("s_waitcnt vmcnt(0)" ::: "memory");
        __builtin_amdgcn_s_barrier();
        __builtin_amdgcn_sched_barrier(0);
        if (it + 2 < NITER) stage(it + 2);
        const char* sA = lbuf[it % 3];
        const char* sB = sA + 4096;
        #pragma unroll
        for (int kk = 0; kk < 2; ++kk) {
            const int kb = kk*64 + (lane>>4)*16;
            const int rr = wm*16 + (lane&15);
            f16x8 af = *(const f16x8*)(sA + rr*128 + (kb ^ ((rr&7)<<4)));
            #pragma unroll
            for (int ni = 0; ni < 2; ++ni) {
                const int oo = wn*32 + ni*16 + (lane&15);
                f16x8 bf = *(const f16x8*)(sB + oo*128 + (kb ^ ((oo&7)<<4)));
                acc[ni] = __builtin_amdgcn_mfma_f32_16x16x32_f16(af, bf, acc[ni], 0, 0, 0);
            }
        }
    }

    // ---- epilogue (R4-proven): D layout col=lane&15, row=(lane>>4)*4+r ----
    #pragma unroll
    for (int r = 0; r < 4; ++r) {
        const int row = m0 + wm*16 + (lane>>4)*4 + r;
        const float c0 = acoef[row*4+0], c1 = acoef[row*4+1],
                    c2 = acoef[row*4+2], c3 = acoef[row*4+3];
        #pragma unroll
        for (int ni = 0; ni < 2; ++ni) {
            const int col = n0 + wn*32 + ni*16 + (lane&15);
            float v = acc[ni][r];
            if (LAYER == 2) {
                if (col < OUT_DIM) {
                    float bi = c0*bias[col] + c1*bias[NB+col]
                             + c2*bias[2*NB+col] + c3*bias[3*NB+col];
                    outF[(size_t)row*OUT_DIM + col] = v + bi;
                }
            } else {
                float bi = c0*bias[col] + c1*bias[NB+col]
                         + c2*bias[2*NB+col] + c3*bias[3*NB+col];
                v += bi;
                v = (v > 0.f) ? v : expm1f(v);
                size_t o = (size_t)row*K12V + col;
                outH[o        ] = __float2half(c0*v);
                outH[o +   HID] = __float2half(c1*v);
                outH[o + 2*HID] = __float2half(c2*v);
                outH[o + 3*HID] = __float2half(c3*v);
            }
        }
    }
}

extern "C" void kernel_launch(void* const* d_in, const int* in_sizes, int n_in,
                              void* d_out, int out_size, void* d_ws, size_t ws_size,
                              hipStream_t stream) {
    const float* x  = (const float*)d_in[0];
    const float* W0 = (const float*)d_in[1];
    const float* W1 = (const float*)d_in[2];
    const float* W2 = (const float*)d_in[3];
    const float* b0 = (const float*)d_in[4];
    const float* b1 = (const float*)d_in[5];
    const float* b2 = (const float*)d_in[6];
    float* out = (float*)d_out;
    float* ws  = (float*)d_ws;

    float*  acoef = ws + OFF_ACOEF;
    __half* X0h   = (__half*)(ws + OFF_X0H);
    __half* W0h   = (__half*)(ws + OFF_W0H);
    __half* W1h   = (__half*)(ws + OFF_W1H);
    __half* W2h   = (__half*)(ws + OFF_W2H);
    __half* H1x   = (__half*)(ws + OFF_H1X);
    __half* H2x   = (__half*)(ws + OFF_H2X);

    prep_all<<<dim3(2368), dim3(256), 0, stream>>>(x, W0, W1, W2, acoef,
                                                   X0h, W0h, W1h, W2h);

    gemm_mfma<0><<<dim3(HID/64, BATCH/32), dim3(256), 0, stream>>>(
        X0h, W0h, acoef, b0, H1x, nullptr);
    gemm_mfma<1><<<dim3(HID/64, BATCH/32), dim3(256), 0, stream>>>(
        H1x, W1h, acoef, b1, H2x, nullptr);
    gemm_mfma<2><<<dim3(320/64, BATCH/32), dim3(256), 0, stream>>>(
        H2x, W2h, acoef, b2, nullptr, out);
}

// Round 10
// 41.872 us; speedup vs baseline: 2.3103x; 1.0859x over previous
//
#include <hip/hip_runtime.h>
#include <hip/hip_fp16.h>
#include <math.h>

typedef _Float16 f16x8 __attribute__((ext_vector_type(8)));
typedef float f32x4 __attribute__((ext_vector_type(4)));

#define NS 4
#define HID 512
#define IN_DIM 342
#define OUT_DIM 311
#define BATCH 1024
#define INP 352            // IN_DIM padded to mult of 32
#define K0V (NS*INP)       // 1408
#define K12V (NS*HID)      // 2048
#define XROW (IN_DIM+1)    // 343

// workspace float offsets (~11.9 MB)
#define OFF_ACOEF 0
#define OFF_X0H   4096
#define OFF_W0H   (OFF_X0H + 720896)
#define OFF_W1H   (OFF_W0H + 360448)
#define OFF_W2H   (OFF_W1H + 524288)
#define OFF_H1X   (OFF_W2H + 327680)
#define OFF_H2X   OFF_X0H      // overlays X0h+part of W0h (dead after L0)

typedef __attribute__((address_space(3))) void lds_t;
typedef __attribute__((address_space(1))) const void gvm_t;
__device__ __forceinline__ void gload16(const void* g, void* l) {
    __builtin_amdgcn_global_load_lds((gvm_t*)g, (lds_t*)l, 16, 0, 0);
}

// ---- fused prep kernel (R4-proven) ----
__global__ __launch_bounds__(256) void prep_all(
    const float* __restrict__ x,
    const float* __restrict__ W0, const float* __restrict__ W1,
    const float* __restrict__ W2,
    float* __restrict__ acoef,
    __half* __restrict__ X0h, __half* __restrict__ W0h,
    __half* __restrict__ W1h, __half* __restrict__ W2h)
{
    const int bid = blockIdx.x;
    const int t = threadIdx.x;
    if (bid < 512) {                       // W0h
        int o = bid;
        for (int k = t; k < K0V; k += 256) {
            int s = k / INP;
            int i = k - s*INP;
            float v = 0.f;
            if (i < IN_DIM) v = W0[((size_t)s*HID + o)*IN_DIM + i];
            W0h[(size_t)o*K0V + k] = __float2half(v);
        }
    } else if (bid < 1024) {               // W1h
        int o = bid - 512;
        int k = t * 8;
        int s = k >> 9, i = k & 511;
        const float* src = W1 + ((size_t)s*HID + o)*HID + i;
        float4 v0 = *(const float4*)(src);
        float4 v1 = *(const float4*)(src + 4);
        f16x8 h;
        h[0]=(_Float16)v0.x; h[1]=(_Float16)v0.y; h[2]=(_Float16)v0.z; h[3]=(_Float16)v0.w;
        h[4]=(_Float16)v1.x; h[5]=(_Float16)v1.y; h[6]=(_Float16)v1.z; h[7]=(_Float16)v1.w;
        *(f16x8*)(W1h + (size_t)o*K12V + k) = h;
    } else if (bid < 1344) {               // W2h
        int o = bid - 1024;                 // 0..319
        int k = t * 8;
        int s = k >> 9, i = k & 511;
        f16x8 h = {};
        if (o < OUT_DIM) {
            const float* src = W2 + ((size_t)s*OUT_DIM + o)*HID + i;
            float4 v0 = *(const float4*)(src);
            float4 v1 = *(const float4*)(src + 4);
            h[0]=(_Float16)v0.x; h[1]=(_Float16)v0.y; h[2]=(_Float16)v0.z; h[3]=(_Float16)v0.w;
            h[4]=(_Float16)v1.x; h[5]=(_Float16)v1.y; h[6]=(_Float16)v1.z; h[7]=(_Float16)v1.w;
        }
        *(f16x8*)(W2h + (size_t)o*K12V + k) = h;
    } else {                               // X0h + acoef
        int b = bid - 1344;
        float phase = x[(size_t)b*XROW + IN_DIM];
        float ps = (float)NS * phase;
        float mu = ps - floorf(ps);
        int i1 = ((int)ps) & (NS-1);
        float mu2 = mu*mu, mu3 = mu2*mu;
        float c1 =  1.5f*mu3 - 2.5f*mu2 + 1.0f;        // rel 0
        float c2 = -1.5f*mu3 + 2.0f*mu2 + 0.5f*mu;     // rel 1
        float c3 =  0.5f*mu3 - 0.5f*mu2;               // rel 2
        float c0 = -0.5f*mu3 +      mu2 - 0.5f*mu;     // rel 3
        if (t < 4) {
            int rel = (t - i1) & 3;
            acoef[b*4 + t] = (rel==0)?c1:(rel==1)?c2:(rel==2)?c3:c0;
        }
        for (int k = t; k < K0V; k += 256) {
            int s = k / INP;
            int i = k - s*INP;
            int rel = (s - i1) & 3;
            float sel = (rel==0)?c1:(rel==1)?c2:(rel==2)?c3:c0;
            float v = (i < IN_DIM) ? x[(size_t)b*XROW + i] * sel : 0.f;
            X0h[(size_t)b*K0V + k] = __float2half(v);
        }
    }
}

// ---- MFMA GEMM, R4 geometry (BM=32 x BN=64, BK=64, 4 waves, acc[2]) ----
// Staging via global_load_lds width-16 into a 4-buffer LDS ring, depth-3
// prefetch, steady-state vmcnt(6) (wait only the oldest slot). LDS dest
// linear; global SOURCE pre-swizzled (XOR involution); ds_reads swizzled.
template<int LAYER>
__global__ __launch_bounds__(256) void gemm_mfma(
    const __half* __restrict__ A,
    const __half* __restrict__ Bw,
    const float* __restrict__ acoef,
    const float* __restrict__ bias,
    __half* __restrict__ outH,
    float* __restrict__ outF)
{
    constexpr int K  = (LAYER==0) ? K0V : K12V;
    constexpr int NB = (LAYER==2) ? OUT_DIM : HID;
    constexpr int NITER = K / 64;

    __shared__ __align__(16) char lbuf[4][12288];   // A 4KB | B 8KB per slot

    const int t    = threadIdx.x;
    const int lane = t & 63;
    const int wid  = t >> 6;
    const int wm   = wid >> 1;
    const int wn   = wid & 1;
    const int m0   = blockIdx.y * 32;
    const int n0   = blockIdx.x * 64;

    // A: LDS byte t*16 -> row r=t>>3, lds-chunk c=t&7; global chunk = c^(r&7)
    const int rA = t >> 3, cA = t & 7;
    const __half* aSrc = A + (size_t)(m0 + rA)*K + ((cA ^ (rA & 7)) * 8);
    // B: two 4KB halves (rows 0..31, 32..63)
    const __half* bSrc0 = Bw + (size_t)(n0 + rA)*K      + ((cA ^ (rA & 7)) * 8);
    const __half* bSrc1 = Bw + (size_t)(n0 + 32 + rA)*K + ((cA ^ (rA & 7)) * 8);
    const int wb = wid * 1024;     // wave-uniform LDS sub-base

    f32x4 acc[2] = {};

    auto stage = [&](int it) {
        char* base = lbuf[it & 3];
        const int ko = it * 64;
        gload16(aSrc  + ko, base        + wb);
        gload16(bSrc0 + ko, base + 4096 + wb);
        gload16(bSrc1 + ko, base + 8192 + wb);
    };

    stage(0);
    stage(1);
    stage(2);

    for (int it = 0; it < NITER; ++it) {
        if (it + 2 < NITER)      asm volatile("s_waitcnt vmcnt(6)" ::: "memory");
        else if (it + 1 < NITER) asm volatile("s_waitcnt vmcnt(3)" ::: "memory");
        else                     asm volatile("s_waitcnt vmcnt(0)" ::: "memory");
        __builtin_amdgcn_s_barrier();
        __builtin_amdgcn_sched_barrier(0);
        if (it + 3 < NITER) stage(it + 3);
        const char* sA = lbuf[it & 3];
        const char* sB = sA + 4096;
        #pragma unroll
        for (int kk = 0; kk < 2; ++kk) {
            const int kb = kk*64 + (lane>>4)*16;
            const int rr = wm*16 + (lane&15);
            f16x8 af = *(const f16x8*)(sA + rr*128 + (kb ^ ((rr&7)<<4)));
            #pragma unroll
            for (int ni = 0; ni < 2; ++ni) {
                const int oo = wn*32 + ni*16 + (lane&15);
                f16x8 bf = *(const f16x8*)(sB + oo*128 + (kb ^ ((oo&7)<<4)));
                acc[ni] = __builtin_amdgcn_mfma_f32_16x16x32_f16(af, bf, acc[ni], 0, 0, 0);
            }
        }
    }

    // ---- epilogue (R4-proven): D layout col=lane&15, row=(lane>>4)*4+r ----
    #pragma unroll
    for (int r = 0; r < 4; ++r) {
        const int row = m0 + wm*16 + (lane>>4)*4 + r;
        const float c0 = acoef[row*4+0], c1 = acoef[row*4+1],
                    c2 = acoef[row*4+2], c3 = acoef[row*4+3];
        #pragma unroll
        for (int ni = 0; ni < 2; ++ni) {
            const int col = n0 + wn*32 + ni*16 + (lane&15);
            float v = acc[ni][r];
            if (LAYER == 2) {
                if (col < OUT_DIM) {
                    float bi = c0*bias[col] + c1*bias[NB+col]
                             + c2*bias[2*NB+col] + c3*bias[3*NB+col];
                    outF[(size_t)row*OUT_DIM + col] = v + bi;
                }
            } else {
                float bi = c0*bias[col] + c1*bias[NB+col]
                         + c2*bias[2*NB+col] + c3*bias[3*NB+col];
                v += bi;
                v = (v > 0.f) ? v : expm1f(v);
                size_t o = (size_t)row*K12V + col;
                outH[o        ] = __float2half(c0*v);
                outH[o +   HID] = __float2half(c1*v);
                outH[o + 2*HID] = __float2half(c2*v);
                outH[o + 3*HID] = __float2half(c3*v);
            }
        }
    }
}

extern "C" void kernel_launch(void* const* d_in, const int* in_sizes, int n_in,
                              void* d_out, int out_size, void* d_ws, size_t ws_size,
                              hipStream_t stream) {
    const float* x  = (const float*)d_in[0];
    const float* W0 = (const float*)d_in[1];
    const float* W1 = (const float*)d_in[2];
    const float* W2 = (const float*)d_in[3];
    const float* b0 = (const float*)d_in[4];
    const float* b1 = (const float*)d_in[5];
    const float* b2 = (const float*)d_in[6];
    float* out = (float*)d_out;
    float* ws  = (float*)d_ws;

    float*  acoef = ws + OFF_ACOEF;
    __half* X0h   = (__half*)(ws + OFF_X0H);
    __half* W0h   = (__half*)(ws + OFF_W0H);
    __half* W1h   = (__half*)(ws + OFF_W1H);
    __half* W2h   = (__half*)(ws + OFF_W2H);
    __half* H1x   = (__half*)(ws + OFF_H1X);
    __half* H2x   = (__half*)(ws + OFF_H2X);

    prep_all<<<dim3(2368), dim3(256), 0, stream>>>(x, W0, W1, W2, acoef,
                                                   X0h, W0h, W1h, W2h);

    gemm_mfma<0><<<dim3(HID/64, BATCH/32), dim3(256), 0, stream>>>(
        X0h, W0h, acoef, b0, H1x, nullptr);
    gemm_mfma<1><<<dim3(HID/64, BATCH/32), dim3(256), 0, stream>>>(
        H1x, W1h, acoef, b1, H2x, nullptr);
    gemm_mfma<2><<<dim3(320/64, BATCH/32), dim3(256), 0, stream>>>(
        H2x, W2h, acoef, b2, nullptr, out);
}